// Round 2
// baseline (255.838 us; speedup 1.0000x reference)
//
#include <hip/hip_runtime.h>
#include <cstdint>
#include <cstddef>

// VQ-VAE quantization forward, MI355X/gfx950 — bf16 split-precision MFMA version.
// dot(x, e_norm) = xh*eh + xh*el + xl*eh  (3x mfma, fp32 accum)
//
// v3: mfma_f32_32x32x16_bf16, 32 rows/wave, 128 rows/block -> grid 200 (<=256 CUs,
// perfect balance, 1 block/CU). LDS B-read traffic per FLOP halved vs 16x16.
// Same double-buffered 32KB chunk staging, counted vmcnt(12), lgkmcnt(8) batches.

typedef __attribute__((ext_vector_type(8)))  short short8;
typedef __attribute__((ext_vector_type(16))) float f32x16;

namespace {
constexpr int kNT = 25600;           // N*T rows
constexpr int kD  = 1024;            // feature dim
constexpr int kM  = 256;             // codebook size
constexpr size_t kQElems = (size_t)kNT * kD;

// ws layout (float units). Codebook images: 32 chunks x [n=256][k=32] bf16,
// 16B sub-blocks swizzled: element idx = c*8192 + n*32 + (g ^ ((n>>1)&3))*8 + (k&7)
constexpr int WS_IMG_H = 0;                    // 262144 ushort = 131072 floats
constexpr int WS_IMG_L = 131072;               // 262144 ushort
constexpr int WS_E2N   = 262144;               // ||e_norm||^2 (256)
constexpr int WS_SCL   = WS_E2N + kM;          // ||e_raw|| + 1e-4 (256)
constexpr int WS_E2R   = WS_SCL + kM;          // ||e_raw||^2 (256)
constexpr int WS_COM   = WS_E2R + kM;          // commitment accumulator
constexpr int WS_HIST  = WS_COM + 4;           // histogram 256 ints
constexpr int WS_ZERO_BYTES = (WS_HIST + kM - WS_COM) * 4;
}

typedef __attribute__((address_space(3))) unsigned int        lds_u32;
typedef const __attribute__((address_space(1))) unsigned int  glb_u32;
typedef const __attribute__((address_space(3))) char          lds_chc;

__device__ __forceinline__ void gl2lds16(const void* g, void* l) {
  __builtin_amdgcn_global_load_lds((glb_u32*)g, (lds_u32*)l, 16, 0, 0);
}

// inline-asm LDS read: compile-time offset immediate; lgkmcnt counted manually
// (rule #18: lgkmcnt asm + sched_barrier(0) before dependent MFMAs).
template <int OFF>
__device__ __forceinline__ short8 ldsr(lds_chc* p) {
  short8 r;
  asm volatile("ds_read_b128 %0, %1 offset:%c2" : "=v"(r) : "v"(p), "i"(OFF));
  return r;
}

// ---------------- kernel 1: normalize codebook -> swizzled bf16 hi/lo images + stats ----
__global__ __launch_bounds__(256) void vq_normalize(const float* __restrict__ emb,
                                                    float* __restrict__ ws) {
  const int m = blockIdx.x;
  const int t = threadIdx.x;
  const float4 v = reinterpret_cast<const float4*>(emb + (size_t)m * kD)[t];
  float s = v.x * v.x + v.y * v.y + v.z * v.z + v.w * v.w;
#pragma unroll
  for (int mask = 32; mask >= 1; mask >>= 1) s += __shfl_xor(s, mask);
  __shared__ float red[4];
  if ((t & 63) == 0) red[t >> 6] = s;
  __syncthreads();
  const float tot = red[0] + red[1] + red[2] + red[3];
  const float sc  = sqrtf(tot) + 1e-4f;
  const float inv = 1.0f / sc;
  const float4 nv = make_float4(v.x * inv, v.y * inv, v.z * inv, v.w * inv);

  float s2 = nv.x * nv.x + nv.y * nv.y + nv.z * nv.z + nv.w * nv.w;
#pragma unroll
  for (int mask = 32; mask >= 1; mask >>= 1) s2 += __shfl_xor(s2, mask);
  __syncthreads();
  if ((t & 63) == 0) red[t >> 6] = s2;
  __syncthreads();
  if (t == 0) {
    ws[WS_E2N + m] = red[0] + red[1] + red[2] + red[3];
    ws[WS_SCL + m] = sc;
    ws[WS_E2R + m] = tot;
  }

  // hi/lo truncation split, packed to the swizzled image
  unsigned short* imgh = (unsigned short*)(ws + WS_IMG_H);
  unsigned short* imgl = (unsigned short*)(ws + WS_IMG_L);
  const int c  = t >> 3;              // k-chunk (k = 4t..4t+3)
  const int g  = (t >> 1) & 3;        // 8-elem group within chunk
  const int sq = g ^ ((m >> 1) & 3);  // bank swizzle
  const int base = c * 8192 + m * 32 + sq * 8 + 4 * (t & 1);
  ushort4 hq, lq;
#pragma unroll
  for (int j = 0; j < 4; ++j) {
    const float fv = (&nv.x)[j];
    const unsigned int b = __float_as_uint(fv);
    const unsigned short hi = (unsigned short)(b >> 16);
    const float lof = fv - __uint_as_float(b & 0xFFFF0000u);
    const unsigned short lo = (unsigned short)(__float_as_uint(lof) >> 16);
    (&hq.x)[j] = hi; (&lq.x)[j] = lo;
  }
  *(ushort4*)(imgh + base) = hq;
  *(ushort4*)(imgl + base) = lq;
}

// ---------------- kernel 2: MFMA distances + argmin + gather + stats ----------------
// 200 blocks x 256 threads (4 waves). Wave w: rows [blk*128 + w*32, +32),
// all 256 codes, full K=1024. Per K-chunk of 32: block stages shared 32KB
// hi+lo codebook chunk into buf[kc&1] while computing on buf[kc^1].
//
// mfma_f32_32x32x16_bf16 fragment maps (gfx950):
//   A: row = l&31, k = (l>>5)*8 + j      B: col = l&31, k = (l>>5)*8 + j
//   C/D: col = l&31, row = (reg&3) + 8*(reg>>2) + 4*(l>>5)

// read hi+lo fragments for 4 column tiles T0..T0+3 from buffer BSEL at base LB
#define RD8T(BSEL, T0, LB, H0, H1, H2, H3, L0, L1, L2, L3)                     \
  H0 = ldsr<(BSEL) * 32768 + ((T0) + 0) * 2048>(LB);                           \
  H1 = ldsr<(BSEL) * 32768 + ((T0) + 1) * 2048>(LB);                           \
  H2 = ldsr<(BSEL) * 32768 + ((T0) + 2) * 2048>(LB);                           \
  H3 = ldsr<(BSEL) * 32768 + ((T0) + 3) * 2048>(LB);                           \
  L0 = ldsr<(BSEL) * 32768 + 16384 + ((T0) + 0) * 2048>(LB);                   \
  L1 = ldsr<(BSEL) * 32768 + 16384 + ((T0) + 1) * 2048>(LB);                   \
  L2 = ldsr<(BSEL) * 32768 + 16384 + ((T0) + 2) * 2048>(LB);                   \
  L3 = ldsr<(BSEL) * 32768 + 16384 + ((T0) + 3) * 2048>(LB);

// 12 MFMAs for tiles T0..T0+3 (3-term split), round-robin -> dep distance 4
#define MM12T(T0, AH, AL, H0, H1, H2, H3, L0, L1, L2, L3)                                          \
  acc[(T0) + 0] = __builtin_amdgcn_mfma_f32_32x32x16_bf16(AH, H0, acc[(T0) + 0], 0, 0, 0);         \
  acc[(T0) + 1] = __builtin_amdgcn_mfma_f32_32x32x16_bf16(AH, H1, acc[(T0) + 1], 0, 0, 0);         \
  acc[(T0) + 2] = __builtin_amdgcn_mfma_f32_32x32x16_bf16(AH, H2, acc[(T0) + 2], 0, 0, 0);         \
  acc[(T0) + 3] = __builtin_amdgcn_mfma_f32_32x32x16_bf16(AH, H3, acc[(T0) + 3], 0, 0, 0);         \
  acc[(T0) + 0] = __builtin_amdgcn_mfma_f32_32x32x16_bf16(AH, L0, acc[(T0) + 0], 0, 0, 0);         \
  acc[(T0) + 1] = __builtin_amdgcn_mfma_f32_32x32x16_bf16(AH, L1, acc[(T0) + 1], 0, 0, 0);         \
  acc[(T0) + 2] = __builtin_amdgcn_mfma_f32_32x32x16_bf16(AH, L2, acc[(T0) + 2], 0, 0, 0);         \
  acc[(T0) + 3] = __builtin_amdgcn_mfma_f32_32x32x16_bf16(AH, L3, acc[(T0) + 3], 0, 0, 0);         \
  acc[(T0) + 0] = __builtin_amdgcn_mfma_f32_32x32x16_bf16(AL, H0, acc[(T0) + 0], 0, 0, 0);         \
  acc[(T0) + 1] = __builtin_amdgcn_mfma_f32_32x32x16_bf16(AL, H1, acc[(T0) + 1], 0, 0, 0);         \
  acc[(T0) + 2] = __builtin_amdgcn_mfma_f32_32x32x16_bf16(AL, H2, acc[(T0) + 2], 0, 0, 0);         \
  acc[(T0) + 3] = __builtin_amdgcn_mfma_f32_32x32x16_bf16(AL, H3, acc[(T0) + 3], 0, 0, 0);

// split one float4-pair (8 consecutive k floats) into hi/lo bf16 A-frags
#define CONV8(F0, F1, AH, AL)                                                  \
  {                                                                            \
    union { short8 v; unsigned short u[8]; } H_, L_;                           \
    const float fx_[8] = {F0.x, F0.y, F0.z, F0.w, F1.x, F1.y, F1.z, F1.w};     \
    _Pragma("unroll")                                                          \
    for (int jj_ = 0; jj_ < 8; ++jj_) {                                        \
      const float fv_ = fx_[jj_];                                              \
      const unsigned int b_ = __float_as_uint(fv_);                            \
      H_.u[jj_] = (unsigned short)(b_ >> 16);                                  \
      const float lo_ = fv_ - __uint_as_float(b_ & 0xFFFF0000u);               \
      L_.u[jj_] = (unsigned short)(__float_as_uint(lo_) >> 16);                \
      x2 += fv_ * fv_;                                                         \
    }                                                                          \
    AH = H_.v; AL = L_.v;                                                      \
  }

// one K-chunk iteration. BSEL = kc&1 (compile-time).
// vmcnt(12) = this iter's 4 x-loads + 8 stage loads stay in flight; everything
// issued before this iteration is forced complete (incl. buf[BSEL] staging).
#define VQ_ITER3(KC, BSEL)                                                     \
  {                                                                            \
    short8 ah0, al0, ah1, al1;                                                 \
    CONV8(xc0, xc1, ah0, al0)      /* k-step 0 of this chunk */                \
    CONV8(xc2, xc3, ah1, al1)      /* k-step 1 of this chunk */                \
    const int kcn_ = ((KC) < 31) ? (KC) + 1 : 31;                              \
    {                                                                          \
      const float* xp_ = xrow + kcn_ * 32;                                     \
      xc0 = *(const float4*)(xp_);                                             \
      xc1 = *(const float4*)(xp_ + 4);                                         \
      xc2 = *(const float4*)(xp_ + 16);                                        \
      xc3 = *(const float4*)(xp_ + 20);                                        \
      const unsigned short* sg_ = simg + ((size_t)kcn_ << 13) + soff;          \
      char* dg_ = &buf[(BSEL) ^ 1][0] + ldst;                                  \
      _Pragma("unroll")                                                        \
      for (int it_ = 0; it_ < 8; ++it_)                                        \
        gl2lds16(sg_ + it_ * 512, dg_ + it_ * 1024);                           \
    }                                                                          \
    asm volatile("s_waitcnt vmcnt(12)" ::: "memory");                          \
    __builtin_amdgcn_s_barrier();                                              \
    asm volatile("" ::: "memory");                                             \
    short8 h0_, h1_, h2_, h3_, l0_, l1_, l2_, l3_;                             \
    short8 h4_, h5_, h6_, h7_, l4_, l5_, l6_, l7_;                             \
    RD8T((BSEL), 0, lb0, h0_, h1_, h2_, h3_, l0_, l1_, l2_, l3_)               \
    RD8T((BSEL), 4, lb0, h4_, h5_, h6_, h7_, l4_, l5_, l6_, l7_)               \
    asm volatile("s_waitcnt lgkmcnt(8)" ::: "memory");                         \
    __builtin_amdgcn_sched_barrier(0);                                         \
    MM12T(0, ah0, al0, h0_, h1_, h2_, h3_, l0_, l1_, l2_, l3_)                 \
    RD8T((BSEL), 0, lb1, h0_, h1_, h2_, h3_, l0_, l1_, l2_, l3_)               \
    asm volatile("s_waitcnt lgkmcnt(8)" ::: "memory");                         \
    __builtin_amdgcn_sched_barrier(0);                                         \
    MM12T(4, ah0, al0, h4_, h5_, h6_, h7_, l4_, l5_, l6_, l7_)                 \
    RD8T((BSEL), 4, lb1, h4_, h5_, h6_, h7_, l4_, l5_, l6_, l7_)               \
    asm volatile("s_waitcnt lgkmcnt(8)" ::: "memory");                         \
    __builtin_amdgcn_sched_barrier(0);                                         \
    MM12T(0, ah1, al1, h0_, h1_, h2_, h3_, l0_, l1_, l2_, l3_)                 \
    asm volatile("s_waitcnt lgkmcnt(0)" ::: "memory");                         \
    __builtin_amdgcn_sched_barrier(0);                                         \
    MM12T(4, ah1, al1, h4_, h5_, h6_, h7_, l4_, l5_, l6_, l7_)                 \
    asm volatile("" ::: "memory");                                             \
    __builtin_amdgcn_s_barrier();                                              \
    asm volatile("" ::: "memory");                                             \
  }

__global__ __launch_bounds__(256, 1) void vq_main(const float* __restrict__ x,
                                                  const float* __restrict__ emb,
                                                  const float* __restrict__ wsc,
                                                  float* __restrict__ out,
                                                  float* __restrict__ commit_sum,
                                                  int* __restrict__ hist) {
  __shared__ char buf[2][32768];   // per buffer: [hi 16KB][lo 16KB] of one k-chunk
  __shared__ float e2n_s[kM], scl_s[kM], e2r_s[kM];

  const int t   = threadIdx.x;
  const int l   = t & 63;
  const int w   = t >> 6;
  const int n32 = l & 31;
  const int hw  = l >> 5;
  const int r0w = blockIdx.x * 128 + w * 32;   // wave's 32 rows
  const int row = r0w + n32;

  e2n_s[t] = wsc[WS_E2N + t];
  scl_s[t] = wsc[WS_SCL + t];
  e2r_s[t] = wsc[WS_E2R + t];

  // staging: wave w copies quarter w of the 32KB [hi|lo] chunk (linear dest)
  const unsigned short* imgH = (const unsigned short*)(wsc + WS_IMG_H);
  const unsigned short* imgL = (const unsigned short*)(wsc + WS_IMG_L);
  const unsigned short* simg = (w & 2) ? imgL : imgH;
  const int soff = (w & 1) * 4096 + l * 8;      // elems within chunk image
  const int ldst = w * 8192;                    // bytes within buf[b]

  const float* xrow = x + (size_t)row * kD + hw * 8;

  // B-frag LDS bases (bank swizzle sq = g ^ ((n>>1)&3), g = ks*2 + hw)
  const int q3  = (n32 >> 1) & 3;
  const int sq0 = hw ^ q3;            // ks = 0
  const int sq1 = (2 + hw) ^ q3;      // ks = 1
  lds_chc* lb0 = (lds_chc*)&buf[0][0] + n32 * 64 + sq0 * 16;
  lds_chc* lb1 = (lds_chc*)&buf[0][0] + n32 * 64 + sq1 * 16;

  f32x16 acc[8];
#pragma unroll
  for (int i = 0; i < 8; ++i) acc[i] = (f32x16)0.0f;
  float x2 = 0.0f;

  // prologue: x for kc=0 and stage chunk 0 -> buf[0]   (12 VMEM ops in flight)
  float4 xc0 = *(const float4*)(xrow);
  float4 xc1 = *(const float4*)(xrow + 4);
  float4 xc2 = *(const float4*)(xrow + 16);
  float4 xc3 = *(const float4*)(xrow + 20);
  {
    const unsigned short* sg = simg + soff;
    char* dg = &buf[0][0] + ldst;
#pragma unroll
    for (int it = 0; it < 8; ++it) gl2lds16(sg + it * 512, dg + it * 1024);
  }

#pragma unroll 1
  for (int kk = 0; kk < 32; kk += 2) {
    VQ_ITER3(kk, 0)
    VQ_ITER3(kk + 1, 1)
  }

  // ---- ||x_row||^2: lane holds the hw-half of row n32; combine halves
  x2 += __shfl_xor(x2, 32);

  // ---- in-register argmin over 256 codes.
  // acc[ct][rg] at lane l = dot(row (rg&3)+8*(rg>>2)+4*hw, code ct*32+n32).
  float bv[16]; int bj[16];
#pragma unroll
  for (int i = 0; i < 16; ++i) { bv[i] = 3.0e38f; bj[i] = 0; }
#pragma unroll
  for (int ct = 0; ct < 8; ++ct) {
    const int j = ct * 32 + n32;
    const float e = e2n_s[j];
#pragma unroll
    for (int rg = 0; rg < 16; ++rg) {
      const float v = e - 2.0f * acc[ct][rg];
      if (v < bv[rg] || (v == bv[rg] && j < bj[rg])) { bv[rg] = v; bj[rg] = j; }
    }
  }
  // butterfly within each 32-lane half (codes spread over n32)
#pragma unroll
  for (int mk = 1; mk <= 16; mk <<= 1) {
#pragma unroll
    for (int rg = 0; rg < 16; ++rg) {
      const float ov = __shfl_xor(bv[rg], mk);
      const int   oj = __shfl_xor(bj[rg], mk);
      if (ov < bv[rg] || (ov == bv[rg] && oj < bj[rg])) { bv[rg] = ov; bj[rg] = oj; }
    }
  }
  // row-select: lane takes row r = n32 (held in reg regr of half hwant)
  const int regr  = (n32 & 3) | ((n32 >> 3) << 2);
  const int hwant = (n32 >> 2) & 1;
  float bvr = bv[0]; int bjr = bj[0];
#pragma unroll
  for (int rg = 1; rg < 16; ++rg)
    if (regr == rg) { bvr = bv[rg]; bjr = bj[rg]; }
  {
    const float ov = __shfl_xor(bvr, 32);
    const int   oj = __shfl_xor(bjr, 32);
    if (hwant != hw) { bvr = ov; bjr = oj; }
  }

  // ---- commitment + histogram
  // ||x - e_raw||^2 = ||x||^2 + ||e_raw||^2 - (e2n - bv)*scl   [(e2n-bv) = 2*dot]
  float cl = x2 + e2r_s[bjr] - (e2n_s[bjr] - bvr) * scl_s[bjr];
#pragma unroll
  for (int mk = 1; mk <= 32; mk <<= 1) cl += __shfl_xor(cl, mk);
  if (l == 0) atomicAdd(commit_sum, cl * 0.5f);   // rows duplicated across halves
  if (hw == 0) atomicAdd(&hist[bjr], 1);

  // ---- gather: quantized row = raw embedding[argmin], 32 rows per wave
  const float4* emb4 = (const float4*)emb;
  float4* out4 = (float4*)out;
#pragma unroll 2
  for (int r = 0; r < 32; ++r) {
    const int j = __shfl(bjr, r);                 // lane r (half 0) owns row r
    const float4* s = emb4 + (size_t)j * (kD / 4);
    float4* d = out4 + (size_t)(r0w + r) * (kD / 4);
#pragma unroll
    for (int c = 0; c < 4; ++c) d[c * 64 + l] = s[c * 64 + l];
  }
}

// ---------------- kernel 3: scalars ----------------
__global__ __launch_bounds__(256) void vq_final(const int* __restrict__ hist,
                                                const float* __restrict__ commit_sum,
                                                float* __restrict__ out) {
  const int t = threadIdx.x;
  const float p = (float)hist[t] * (1.0f / (float)kNT);
  float s = p * logf(p + 1e-10f);
#pragma unroll
  for (int mask = 32; mask >= 1; mask >>= 1) s += __shfl_xor(s, mask);
  __shared__ float red[4];
  if ((t & 63) == 0) red[t >> 6] = s;
  __syncthreads();
  if (t == 0) {
    const float ent = red[0] + red[1] + red[2] + red[3];
    out[kQElems]     = commit_sum[0] * (1.0f / (float)kQElems);
    out[kQElems + 1] = expf(-ent);
  }
}

extern "C" void kernel_launch(void* const* d_in, const int* in_sizes, int n_in,
                              void* d_out, int out_size, void* d_ws, size_t ws_size,
                              hipStream_t stream) {
  (void)in_sizes; (void)n_in; (void)out_size; (void)ws_size;
  const float* x   = (const float*)d_in[0];
  const float* emb = (const float*)d_in[1];
  float* out = (float*)d_out;
  float* ws  = (float*)d_ws;

  hipMemsetAsync((char*)d_ws + (size_t)WS_COM * 4, 0, WS_ZERO_BYTES, stream);
  hipLaunchKernelGGL(vq_normalize, dim3(kM), dim3(256), 0, stream, emb, ws);
  hipLaunchKernelGGL(vq_main, dim3(kNT / 128), dim3(256), 0, stream,
                     x, emb, ws, out, ws + WS_COM, (int*)(ws + WS_HIST));
  hipLaunchKernelGGL(vq_final, dim3(1), dim3(256), 0, stream,
                     (const int*)(ws + WS_HIST), ws + WS_COM, out);
}